// Round 4
// baseline (574.814 us; speedup 1.0000x reference)
//
#include <hip/hip_runtime.h>
#include <hip/hip_bf16.h>
#include <math.h>

#define NTOK 4096   // B*L
#define DM   2048   // model dim
#define NE   8      // experts
#define BK2  32     // K per tile
#define NT   64     // K tiles (2048/32)
#define TILE_BYTES 32768   // A 16KB + B 16KB
#define B_OFF      16384

using f32x4  = float __attribute__((ext_vector_type(4)));
using bf16x8 = __bf16 __attribute__((ext_vector_type(8)));
using u32x4  = unsigned int __attribute__((ext_vector_type(4)));

#define SBAR()  __builtin_amdgcn_s_barrier()
#define SCHED() __builtin_amdgcn_sched_barrier(0)

__device__ __forceinline__ unsigned short bf16bits(float f){
  unsigned u = __builtin_bit_cast(unsigned, f);
  return (unsigned short)((u + 0x7fffu + ((u >> 16) & 1u)) >> 16);  // RNE
}

__device__ __forceinline__ void load_lds16(const void* g, void* l){
  __builtin_amdgcn_global_load_lds(
      (const __attribute__((address_space(1))) unsigned int*)g,
      (__attribute__((address_space(3))) unsigned int*)l, 16, 0, 0);
}

// ---------------- router: rms-scale -> logits -> softmax -> top2 -> bucketize; also x->bf16
__global__ __launch_bounds__(256) void router_kernel(
    const float* __restrict__ x, const float* __restrict__ rs,
    const float* __restrict__ gw, const float* __restrict__ pes,
    unsigned short* __restrict__ xbf, int* __restrict__ cnt,
    int* __restrict__ toklist, float* __restrict__ slotw,
    int* __restrict__ tok2slot)
{
  const int wv = threadIdx.x >> 6, l = threadIdx.x & 63;
  const int n = blockIdx.x * 4 + wv;            // one wave per token
  const float* xr = x + (size_t)n * DM;
  unsigned short* xb = xbf + (size_t)n * DM;
  float ssq = 0.f;
  float lg[8] = {0,0,0,0,0,0,0,0};
  #pragma unroll
  for (int q = 0; q < 8; ++q){
    int c4 = l + 64 * q;                         // float4 chunk
    float4 v = ((const float4*)xr)[c4];
    float4 r = ((const float4*)rs)[c4];
    ssq += v.x*v.x + v.y*v.y + v.z*v.z + v.w*v.w;
    ushort4 o; o.x = bf16bits(v.x); o.y = bf16bits(v.y); o.z = bf16bits(v.z); o.w = bf16bits(v.w);
    ((ushort4*)xb)[c4] = o;
    float xs0 = v.x*r.x, xs1 = v.y*r.y, xs2 = v.z*r.z, xs3 = v.w*r.w;
    const float4* gp = (const float4*)(gw + (size_t)c4 * 32); // 4 rows x 8 experts
    float4 ga, gb;
    ga = gp[0]; gb = gp[1];
    lg[0]+=xs0*ga.x; lg[1]+=xs0*ga.y; lg[2]+=xs0*ga.z; lg[3]+=xs0*ga.w;
    lg[4]+=xs0*gb.x; lg[5]+=xs0*gb.y; lg[6]+=xs0*gb.z; lg[7]+=xs0*gb.w;
    ga = gp[2]; gb = gp[3];
    lg[0]+=xs1*ga.x; lg[1]+=xs1*ga.y; lg[2]+=xs1*ga.z; lg[3]+=xs1*ga.w;
    lg[4]+=xs1*gb.x; lg[5]+=xs1*gb.y; lg[6]+=xs1*gb.z; lg[7]+=xs1*gb.w;
    ga = gp[4]; gb = gp[5];
    lg[0]+=xs2*ga.x; lg[1]+=xs2*ga.y; lg[2]+=xs2*ga.z; lg[3]+=xs2*ga.w;
    lg[4]+=xs2*gb.x; lg[5]+=xs2*gb.y; lg[6]+=xs2*gb.z; lg[7]+=xs2*gb.w;
    ga = gp[6]; gb = gp[7];
    lg[0]+=xs3*ga.x; lg[1]+=xs3*ga.y; lg[2]+=xs3*ga.z; lg[3]+=xs3*ga.w;
    lg[4]+=xs3*gb.x; lg[5]+=xs3*gb.y; lg[6]+=xs3*gb.z; lg[7]+=xs3*gb.w;
  }
  #pragma unroll
  for (int off = 32; off; off >>= 1){
    ssq += __shfl_xor(ssq, off, 64);
    #pragma unroll
    for (int e2 = 0; e2 < 8; ++e2) lg[e2] += __shfl_xor(lg[e2], off, 64);
  }
  if (l == 0){
    float c = rsqrtf(ssq * (1.0f/DM) + 1e-6f) * 0.022097086912079608f; // rms * D^-0.5
    float mx = -1e30f;
    #pragma unroll
    for (int e2 = 0; e2 < 8; ++e2){ lg[e2] *= c; mx = fmaxf(mx, lg[e2]); }
    float l0 = lg[0]; int i0 = 0;
    #pragma unroll
    for (int e2 = 1; e2 < 8; ++e2) if (lg[e2] > l0){ l0 = lg[e2]; i0 = e2; }
    int i1 = (i0 == 0) ? 1 : 0; float l1 = (i0 == 0) ? lg[1] : lg[0];
    #pragma unroll
    for (int e2 = 0; e2 < 8; ++e2){ if (e2 != i0 && lg[e2] > l1){ l1 = lg[e2]; i1 = e2; } }
    float p0 = expf(l0 - mx), p1 = expf(l1 - mx);
    float sw = fmaxf(p0 + p1, 1e-12f);
    float w0 = p0 / sw, w1 = p1 / sw;
    int s0 = atomicAdd(&cnt[i0], 1);
    toklist[i0 * NTOK + s0] = n;
    slotw[i0 * NTOK + s0] = w0 * pes[i0];
    tok2slot[2 * n] = (i0 << 16) | s0;
    int s1 = atomicAdd(&cnt[i1], 1);
    toklist[i1 * NTOK + s1] = n;
    slotw[i1 * NTOK + s1] = w1 * pes[i1];
    tok2slot[2 * n + 1] = (i1 << 16) | s1;
  }
}

__global__ void scan_kernel(const int* __restrict__ cnt, int* __restrict__ basep){
  if (threadIdx.x == 0){
    int a = 0;
    for (int e = 0; e < NE; ++e){ basep[e] = a; a += cnt[e]; }
  }
}

// ---------------- weight convert + transpose: W fp32 [2048 k][ncols n] -> Wt bf16 [ncols n][2048 k]
__global__ __launch_bounds__(256) void conv_transpose_kernel(
    const float* __restrict__ W, unsigned short* __restrict__ Wt, int ncols)
{
  const int z = blockIdx.z;
  const float* src = W + (size_t)z * 2048 * ncols;
  unsigned short* dst = Wt + (size_t)z * ncols * 2048;
  const int n0 = blockIdx.x * 64, k0 = blockIdx.y * 64;
  __shared__ __align__(16) unsigned short t[64][72];
  const int tid = threadIdx.x;
  const int kl = tid >> 4;
  const int nl = (tid & 15) * 4;
  #pragma unroll
  for (int q = 0; q < 4; ++q){
    int k = kl + q * 16;
    float4 v = *(const float4*)(src + (size_t)(k0 + k) * ncols + n0 + nl);
    t[nl+0][k] = bf16bits(v.x);
    t[nl+1][k] = bf16bits(v.y);
    t[nl+2][k] = bf16bits(v.z);
    t[nl+3][k] = bf16bits(v.w);
  }
  __syncthreads();
  const int nr = tid >> 3;
  const int k8 = (tid & 7) * 8;
  #pragma unroll
  for (int q = 0; q < 2; ++q){
    int n = nr + q * 32;
    u32x4 v = *(const u32x4*)&t[n][k8];
    *(u32x4*)(dst + (size_t)(n0 + n) * 2048 + k0 + k8) = v;
  }
}

// ---------------- grouped GEMM, phase-pipelined: 256x256 tile, BK=32, 8 waves (2x4),
// 4-deep LDS ring, counted vmcnt(8), raw s_barrier + sched_barrier(0) pins (NO memory
// clobbers -> compiler must not drain vmcnt/lgkmcnt at barriers). setprio around MFMA.
// MODE 0: 256 x (128 gate + 128 up); gelu(g)*u -> act bf16. MODE 1: 256x256 -> ybuf bf16.
template<int MODE>
__global__ __launch_bounds__(512, 1) void moe_gemm(
    const unsigned short* __restrict__ Abuf,   // xbf (MODE0) / act (MODE1)
    const unsigned short* __restrict__ Wt,     // bf16 [z][ncols][2048]
    unsigned short* __restrict__ act,
    unsigned short* __restrict__ ybuf,
    const int* __restrict__ cnt,
    const int* __restrict__ basep,
    const int* __restrict__ toklist,
    int e0)
{
  // ---- XCD-chunked bijective remap: same-fb blocks colocate per XCD
  const int gx = gridDim.x, gy = gridDim.y, gz = gridDim.z;
  int flat = blockIdx.x + gx * (blockIdx.y + gy * blockIdx.z);
  int per  = (gx * gy * gz) >> 3;
  int id2  = (flat & 7) * per + (flat >> 3);
  int fpb  = gy * gz;           // blocks per fb value
  int fbi  = id2 / fpb;
  int rem  = id2 % fpb;
  const int z  = rem / gy;
  const int e  = e0 + z;
  const int ce = cnt[e];
  const int m0 = (rem % gy) * 256;
  if (m0 >= ce) return;
  const int fb = fbi * (MODE == 0 ? 128 : 256);
  const int tid = threadIdx.x;
  const int l = tid & 63;
  const int wv = tid >> 6;        // 0..7
  const int wr = wv >> 2;         // row half (128 rows each)
  const int wc = wv & 3;          // col group (64 cols each)
  const int baseE = basep[e];
  const size_t ncols = (MODE == 0) ? 4096 : 2048;
  const unsigned short* Wz = Wt + (size_t)z * ncols * 2048;

  __shared__ __align__(16) unsigned short smem[4 * TILE_BYTES / 2];  // 128 KiB

  // per-thread staging sources (16B chunks; source k-granule pre-swizzled)
  const unsigned short* asrc[2];
  #pragma unroll
  for (int q = 0; q < 2; ++q){
    int r = q * 128 + (tid >> 2);
    int g = (tid & 3) ^ ((r >> 1) & 3);
    long rsrc;
    if (MODE == 0) rsrc = toklist[e * NTOK + min(m0 + r, ce - 1)];
    else           rsrc = baseE + min(m0 + r, ce - 1);
    asrc[q] = Abuf + (size_t)rsrc * 2048 + g * 8;
  }
  const unsigned short* bsrc[2];
  #pragma unroll
  for (int q = 0; q < 2; ++q){
    int col = q * 128 + (tid >> 2);
    int g = (tid & 3) ^ ((col >> 1) & 3);
    int n;
    if (MODE == 0){ int sub = col & 63; n = fb + (col >> 6) * 32 + (sub & 31) + ((sub & 32) ? 2048 : 0); }
    else n = fb + col;
    bsrc[q] = Wz + (size_t)n * 2048 + g * 8;
  }
  const int ldst = tid * 16;   // linear LDS byte offset within chunk

  // fragment read offsets (bytes within a tile buffer)
  const int kq = l >> 4;
  const int swz = (kq ^ (((l & 15) >> 1) & 3)) * 16;
  const int abase = (wr * 128 + (l & 15)) * 64 + swz;            // + mi*1024
  const int bbase = B_OFF + (wc * 64 + (l & 15)) * 64 + swz;     // + ni*1024

  f32x4 acc[8][4];
  #pragma unroll
  for (int i = 0; i < 8; ++i)
    #pragma unroll
    for (int j = 0; j < 4; ++j)
      acc[i][j] = (f32x4){0.f, 0.f, 0.f, 0.f};

  auto stage_a = [&](int buf, int st){
    char* base = (char*)smem + buf * TILE_BYTES;
    load_lds16(asrc[0] + st * BK2, base + ldst);
    load_lds16(asrc[1] + st * BK2, base + 8192 + ldst);
  };
  auto stage_b = [&](int buf, int st){
    char* base = (char*)smem + buf * TILE_BYTES + B_OFF;
    load_lds16(bsrc[0] + st * BK2, base + ldst);
    load_lds16(bsrc[1] + st * BK2, base + 8192 + ldst);
  };

  // prologue: stage tiles 0,1,2 (12 loads/thread); wait oldest 4 (tile 0)
  stage_a(0, 0); stage_b(0, 0);
  stage_a(1, 1); stage_b(1, 1);
  stage_a(2, 2); stage_b(2, 2);
  asm volatile("s_waitcnt vmcnt(8)");
  SCHED();
  SBAR();
  SCHED();

  #pragma unroll 1
  for (int kt = 0; kt < NT; ++kt){
    const char* C = (const char*)smem + (kt & 3) * TILE_BYTES;
    const int sb = (kt + 3) & 3;
    const int st = min(kt + 3, NT - 1);
    bf16x8 af[4], bfr[4];
    // ---- phase 1: read B(all) + A(mi0-3); stage next A; barrier; MFMA mi0-3
    #pragma unroll
    for (int ni = 0; ni < 4; ++ni) bfr[ni] = *(const bf16x8*)(C + bbase + ni * 1024);
    #pragma unroll
    for (int mi = 0; mi < 4; ++mi) af[mi] = *(const bf16x8*)(C + abase + mi * 1024);
    stage_a(sb, st);
    SCHED();
    SBAR();
    SCHED();
    __builtin_amdgcn_s_setprio(1);
    #pragma unroll
    for (int ni = 0; ni < 4; ++ni)
      #pragma unroll
      for (int mi = 0; mi < 4; ++mi)
        acc[mi][ni] = __builtin_amdgcn_mfma_f32_16x16x32_bf16(af[mi], bfr[ni], acc[mi][ni], 0, 0, 0);
    __builtin_amdgcn_s_setprio(0);
    SCHED();
    SBAR();
    SCHED();
    // ---- phase 2: read A(mi4-7); stage next B; barrier; MFMA mi4-7; counted drain
    #pragma unroll
    for (int mi = 0; mi < 4; ++mi) af[mi] = *(const bf16x8*)(C + abase + (mi + 4) * 1024);
    stage_b(sb, st);
    SCHED();
    SBAR();
    SCHED();
    __builtin_amdgcn_s_setprio(1);
    #pragma unroll
    for (int ni = 0; ni < 4; ++ni)
      #pragma unroll
      for (int mi = 0; mi < 4; ++mi)
        acc[mi + 4][ni] = __builtin_amdgcn_mfma_f32_16x16x32_bf16(af[mi], bfr[ni], acc[mi + 4][ni], 0, 0, 0);
    __builtin_amdgcn_s_setprio(0);
    SCHED();
    asm volatile("s_waitcnt vmcnt(8)");   // oldest (tile kt+1) complete
    SCHED();
    SBAR();
    SCHED();
  }
  asm volatile("s_waitcnt vmcnt(0)");     // drain dummy tail stages before LDS dealloc
  SCHED();

  const int lq4 = (l >> 4) * 4;
  if (MODE == 0){
    #pragma unroll
    for (int mi = 0; mi < 8; ++mi)
      #pragma unroll
      for (int j = 0; j < 4; ++j){
        int s = m0 + wr * 128 + mi * 16 + lq4 + j;
        if (s < ce){
          size_t rowb = (size_t)(baseE + s) * 2048;
          #pragma unroll
          for (int p = 0; p < 2; ++p){
            float g = acc[mi][p][j];
            float u = acc[mi][p + 2][j];
            float a = 0.5f * g * (1.0f + erff(g * 0.70710678118654752f)) * u; // exact gelu * up
            act[rowb + fb + wc * 32 + p * 16 + (l & 15)] = bf16bits(a);
          }
        }
      }
  } else {
    #pragma unroll
    for (int mi = 0; mi < 8; ++mi)
      #pragma unroll
      for (int j = 0; j < 4; ++j){
        int s = m0 + wr * 128 + mi * 16 + lq4 + j;
        if (s < ce){
          unsigned short* yr = ybuf + (size_t)(baseE + s) * 2048 + fb + wc * 64 + (l & 15);
          #pragma unroll
          for (int ni = 0; ni < 4; ++ni)
            yr[ni * 16] = bf16bits(acc[mi][ni][j]);
        }
      }
  }
}

// ---------------- combine: out[tok] = sum_k slotw[k] * ybuf[slot_k]  (fp32 out, bf16 y)
__global__ __launch_bounds__(256) void combine_kernel(
    const unsigned short* __restrict__ ybuf, const int* __restrict__ tok2slot,
    const float* __restrict__ slotw, const int* __restrict__ basep,
    float* __restrict__ out)
{
  const int n = blockIdx.x * 4 + (threadIdx.x >> 6);
  const int l = threadIdx.x & 63;
  int p0 = tok2slot[2 * n], p1 = tok2slot[2 * n + 1];
  int e0 = p0 >> 16, s0 = p0 & 0xffff;
  int e1 = p1 >> 16, s1 = p1 & 0xffff;
  float w0 = slotw[e0 * NTOK + s0], w1 = slotw[e1 * NTOK + s1];
  const unsigned short* y0 = ybuf + (size_t)(basep[e0] + s0) * 2048;
  const unsigned short* y1 = ybuf + (size_t)(basep[e1] + s1) * 2048;
  float* o = out + (size_t)n * 2048;
  #pragma unroll
  for (int q = 0; q < 4; ++q){
    int c8 = (l + 64 * q) * 8;
    u32x4 a = *(const u32x4*)(y0 + c8);
    u32x4 b = *(const u32x4*)(y1 + c8);
    float rr[8];
    #pragma unroll
    for (int i = 0; i < 4; ++i){
      float a0 = __builtin_bit_cast(float, a[i] << 16);
      float a1 = __builtin_bit_cast(float, a[i] & 0xffff0000u);
      float b0 = __builtin_bit_cast(float, b[i] << 16);
      float b1 = __builtin_bit_cast(float, b[i] & 0xffff0000u);
      rr[2*i]   = w0 * a0 + w1 * b0;
      rr[2*i+1] = w0 * a1 + w1 * b1;
    }
    float4 v0 = {rr[0], rr[1], rr[2], rr[3]};
    float4 v1 = {rr[4], rr[5], rr[6], rr[7]};
    *(float4*)(o + c8) = v0;
    *(float4*)(o + c8 + 4) = v1;
  }
}

extern "C" void kernel_launch(void* const* d_in, const int* in_sizes, int n_in,
                              void* d_out, int out_size, void* d_ws, size_t ws_size,
                              hipStream_t stream)
{
  const float* x   = (const float*)d_in[0];
  const float* rs  = (const float*)d_in[1];
  const float* gw  = (const float*)d_in[2];
  const float* w1  = (const float*)d_in[3];
  const float* w2  = (const float*)d_in[4];
  const float* pes = (const float*)d_in[5];
  float* out = (float*)d_out;

  // ws layout: cnt | base | toklist(128K) | slotw(128K) | tok2slot(32K) |
  //            xbf 16MB | act 32MB | ybuf 32MB | Wt region (EG*16MB)
  char* ws = (char*)d_ws;
  int*   cnt      = (int*)ws;
  int*   basep    = (int*)(ws + 64);
  int*   toklist  = (int*)(ws + 256);
  float* slotw    = (float*)(ws + 256 + (size_t)NE * NTOK * 4);
  int*   tok2slot = (int*)(ws + 256 + 2 * (size_t)NE * NTOK * 4);
  unsigned short* xbf  = (unsigned short*)(ws + 256 + 2 * (size_t)NE * NTOK * 4 + (size_t)NTOK * 8);
  unsigned short* act  = xbf + (size_t)NTOK * DM;
  unsigned short* ybuf = act + (size_t)2 * NTOK * DM;
  unsigned short* wtb  = ybuf + (size_t)2 * NTOK * DM;

  const size_t fixed = (size_t)((char*)wtb - ws);
  const size_t per_e = (size_t)4096 * 2048 * 2;   // 16 MiB (W1 per expert; W2 uses half)
  int EG = NE;
  while (EG > 1 && fixed + (size_t)EG * per_e > ws_size) EG >>= 1;

  hipMemsetAsync(cnt, 0, 64, stream);
  router_kernel<<<NTOK / 4, 256, 0, stream>>>(x, rs, gw, pes, xbf, cnt, toklist, slotw, tok2slot);
  scan_kernel<<<1, 64, 0, stream>>>(cnt, basep);

  for (int g = 0; g < NE; g += EG){
    conv_transpose_kernel<<<dim3(64, 32, EG), 256, 0, stream>>>(
        w1 + (size_t)g * 2048 * 4096, wtb, 4096);
    moe_gemm<0><<<dim3(16, 16, EG), 512, 0, stream>>>(
        xbf, wtb, act, ybuf, cnt, basep, toklist, g);
  }
  for (int g = 0; g < NE; g += EG){
    conv_transpose_kernel<<<dim3(32, 32, EG), 256, 0, stream>>>(
        w2 + (size_t)g * 2048 * 2048, wtb, 2048);
    moe_gemm<1><<<dim3(8, 16, EG), 512, 0, stream>>>(
        act, wtb, act, ybuf, cnt, basep, toklist, g);
  }
  combine_kernel<<<NTOK / 4, 256, 0, stream>>>(ybuf, tok2slot, slotw, basep, out);
}

// Round 5
// 528.740 us; speedup vs baseline: 1.0871x; 1.0871x over previous
//
#include <hip/hip_runtime.h>
#include <hip/hip_bf16.h>
#include <math.h>

#define NTOK 4096   // B*L
#define DM   2048   // model dim
#define NE   8      // experts
#define NKT  32     // K-tiles of 64 (K=2048)

using f32x4  = float __attribute__((ext_vector_type(4)));
using bf16x8 = __bf16 __attribute__((ext_vector_type(8)));
using u32x4  = unsigned int __attribute__((ext_vector_type(4)));

#define SBAR()  __builtin_amdgcn_s_barrier()
#define SCHED() __builtin_amdgcn_sched_barrier(0)

__device__ __forceinline__ unsigned short bf16bits(float f){
  unsigned u = __builtin_bit_cast(unsigned, f);
  return (unsigned short)((u + 0x7fffu + ((u >> 16) & 1u)) >> 16);  // RNE
}

__device__ __forceinline__ void load_lds16(const void* g, void* l){
  __builtin_amdgcn_global_load_lds(
      (const __attribute__((address_space(1))) unsigned int*)g,
      (__attribute__((address_space(3))) unsigned int*)l, 16, 0, 0);
}

__device__ __forceinline__ unsigned lds_addr(const void* p){
  return (unsigned)(unsigned long long)
      (__attribute__((address_space(3))) const char*)p;
}

// asm ds_read_b128: opaque to compiler alias analysis -> no auto vmcnt(0) drains
template<int IMM>
__device__ __forceinline__ bf16x8 lds_read16(unsigned addr){
  u32x4 r;
  asm volatile("ds_read_b128 %0, %1 offset:%c2" : "=v"(r) : "v"(addr), "i"(IMM));
  return __builtin_bit_cast(bf16x8, r);
}

// ---------------- router: rms-scale -> logits -> softmax -> top2 -> bucketize; also x->bf16
__global__ __launch_bounds__(256) void router_kernel(
    const float* __restrict__ x, const float* __restrict__ rs,
    const float* __restrict__ gw, const float* __restrict__ pes,
    unsigned short* __restrict__ xbf, int* __restrict__ cnt,
    int* __restrict__ toklist, float* __restrict__ slotw,
    int* __restrict__ tok2slot)
{
  const int wv = threadIdx.x >> 6, l = threadIdx.x & 63;
  const int n = blockIdx.x * 4 + wv;            // one wave per token
  const float* xr = x + (size_t)n * DM;
  unsigned short* xb = xbf + (size_t)n * DM;
  float ssq = 0.f;
  float lg[8] = {0,0,0,0,0,0,0,0};
  #pragma unroll
  for (int q = 0; q < 8; ++q){
    int c4 = l + 64 * q;                         // float4 chunk
    float4 v = ((const float4*)xr)[c4];
    float4 r = ((const float4*)rs)[c4];
    ssq += v.x*v.x + v.y*v.y + v.z*v.z + v.w*v.w;
    ushort4 o; o.x = bf16bits(v.x); o.y = bf16bits(v.y); o.z = bf16bits(v.z); o.w = bf16bits(v.w);
    ((ushort4*)xb)[c4] = o;
    float xs0 = v.x*r.x, xs1 = v.y*r.y, xs2 = v.z*r.z, xs3 = v.w*r.w;
    const float4* gp = (const float4*)(gw + (size_t)c4 * 32); // 4 rows x 8 experts
    float4 ga, gb;
    ga = gp[0]; gb = gp[1];
    lg[0]+=xs0*ga.x; lg[1]+=xs0*ga.y; lg[2]+=xs0*ga.z; lg[3]+=xs0*ga.w;
    lg[4]+=xs0*gb.x; lg[5]+=xs0*gb.y; lg[6]+=xs0*gb.z; lg[7]+=xs0*gb.w;
    ga = gp[2]; gb = gp[3];
    lg[0]+=xs1*ga.x; lg[1]+=xs1*ga.y; lg[2]+=xs1*ga.z; lg[3]+=xs1*ga.w;
    lg[4]+=xs1*gb.x; lg[5]+=xs1*gb.y; lg[6]+=xs1*gb.z; lg[7]+=xs1*gb.w;
    ga = gp[4]; gb = gp[5];
    lg[0]+=xs2*ga.x; lg[1]+=xs2*ga.y; lg[2]+=xs2*ga.z; lg[3]+=xs2*ga.w;
    lg[4]+=xs2*gb.x; lg[5]+=xs2*gb.y; lg[6]+=xs2*gb.z; lg[7]+=xs2*gb.w;
    ga = gp[6]; gb = gp[7];
    lg[0]+=xs3*ga.x; lg[1]+=xs3*ga.y; lg[2]+=xs3*ga.z; lg[3]+=xs3*ga.w;
    lg[4]+=xs3*gb.x; lg[5]+=xs3*gb.y; lg[6]+=xs3*gb.z; lg[7]+=xs3*gb.w;
  }
  #pragma unroll
  for (int off = 32; off; off >>= 1){
    ssq += __shfl_xor(ssq, off, 64);
    #pragma unroll
    for (int e2 = 0; e2 < 8; ++e2) lg[e2] += __shfl_xor(lg[e2], off, 64);
  }
  if (l == 0){
    float c = rsqrtf(ssq * (1.0f/DM) + 1e-6f) * 0.022097086912079608f; // rms * D^-0.5
    float mx = -1e30f;
    #pragma unroll
    for (int e2 = 0; e2 < 8; ++e2){ lg[e2] *= c; mx = fmaxf(mx, lg[e2]); }
    float l0 = lg[0]; int i0 = 0;
    #pragma unroll
    for (int e2 = 1; e2 < 8; ++e2) if (lg[e2] > l0){ l0 = lg[e2]; i0 = e2; }
    int i1 = (i0 == 0) ? 1 : 0; float l1 = (i0 == 0) ? lg[1] : lg[0];
    #pragma unroll
    for (int e2 = 0; e2 < 8; ++e2){ if (e2 != i0 && lg[e2] > l1){ l1 = lg[e2]; i1 = e2; } }
    float p0 = expf(l0 - mx), p1 = expf(l1 - mx);
    float sw = fmaxf(p0 + p1, 1e-12f);
    float w0 = p0 / sw, w1 = p1 / sw;
    int s0 = atomicAdd(&cnt[i0], 1);
    toklist[i0 * NTOK + s0] = n;
    slotw[i0 * NTOK + s0] = w0 * pes[i0];
    tok2slot[2 * n] = (i0 << 16) | s0;
    int s1 = atomicAdd(&cnt[i1], 1);
    toklist[i1 * NTOK + s1] = n;
    slotw[i1 * NTOK + s1] = w1 * pes[i1];
    tok2slot[2 * n + 1] = (i1 << 16) | s1;
  }
}

__global__ void scan_kernel(const int* __restrict__ cnt, int* __restrict__ basep){
  if (threadIdx.x == 0){
    int a = 0;
    for (int e = 0; e < NE; ++e){ basep[e] = a; a += cnt[e]; }
  }
}

// ---------------- weight convert + transpose: W fp32 [2048 k][ncols n] -> Wt bf16 [ncols n][2048 k]
__global__ __launch_bounds__(256) void conv_transpose_kernel(
    const float* __restrict__ W, unsigned short* __restrict__ Wt, int ncols)
{
  const int z = blockIdx.z;
  const float* src = W + (size_t)z * 2048 * ncols;
  unsigned short* dst = Wt + (size_t)z * ncols * 2048;
  const int n0 = blockIdx.x * 64, k0 = blockIdx.y * 64;
  __shared__ __align__(16) unsigned short t[64][72];
  const int tid = threadIdx.x;
  const int kl = tid >> 4;
  const int nl = (tid & 15) * 4;
  #pragma unroll
  for (int q = 0; q < 4; ++q){
    int k = kl + q * 16;
    float4 v = *(const float4*)(src + (size_t)(k0 + k) * ncols + n0 + nl);
    t[nl+0][k] = bf16bits(v.x);
    t[nl+1][k] = bf16bits(v.y);
    t[nl+2][k] = bf16bits(v.z);
    t[nl+3][k] = bf16bits(v.w);
  }
  __syncthreads();
  const int nr = tid >> 3;
  const int k8 = (tid & 7) * 8;
  #pragma unroll
  for (int q = 0; q < 2; ++q){
    int n = nr + q * 32;
    u32x4 v = *(const u32x4*)&t[n][k8];
    *(u32x4*)(dst + (size_t)(n0 + n) * 2048 + k0 + k8) = v;
  }
}

// ---------------- grouped GEMM, m201-style 4-phase/K-tile pipeline.
// 256x256 tile, BK=64, 8 waves (2M x 4N), per-wave C = 128x64 (acc[8][4]).
// LDS: 2 bufs x 4 pieces (A_k0,A_k1,B_k0,B_k1) x 16KB = 128 KiB.
// Piece = 256 rows x 32 k bf16, row-major 64B rows, granule swizzle pg = kq ^ ((row>>1)&3).
// Phase (s=kstep half, h=mi half): asm ds_reads + stage 1 piece + barrier + lgkmcnt(0)
// + 16 MFMA + barrier. vmcnt(8) at ends of phases 1 and 3 (piece-retirement ledger:
// every piece staged 6 phases before first read, guaranteed by the vmcnt preceding it).
template<int MODE>
__global__ __launch_bounds__(512, 2) void moe_gemm(
    const unsigned short* __restrict__ Abuf,   // xbf (MODE0) / act (MODE1)
    const unsigned short* __restrict__ Wt,     // bf16 [z][ncols][2048]
    unsigned short* __restrict__ act,
    unsigned short* __restrict__ ybuf,
    const int* __restrict__ cnt,
    const int* __restrict__ basep,
    const int* __restrict__ toklist,
    int e0)
{
  const int z = blockIdx.z, e = e0 + z;
  const int ce = cnt[e];
  const int m0 = blockIdx.y * 256;
  if (m0 >= ce) return;
  const int fb = blockIdx.x * (MODE == 0 ? 128 : 256);
  const int tid = threadIdx.x;
  const int l = tid & 63;
  const int wv = tid >> 6;        // 0..7
  const int wr = wv >> 2;         // row half (128 rows)
  const int wc = wv & 3;          // col quarter (64 cols)
  const int baseE = basep[e];
  const size_t ncols = (MODE == 0) ? 4096 : 2048;
  const unsigned short* Wz = Wt + (size_t)z * ncols * 2048;

  __shared__ __align__(16) unsigned char smem[2][4][16384];   // [buf][piece][bytes]

  // staging sources: chunk c = q*512+tid -> row/col = c>>2, phys granule c&3,
  // logical granule g = (c&3) ^ ((row>>1)&3); src pre-offset by g*8 elements.
  const unsigned short* asrcp[2];
  const unsigned short* bsrcp[2];
  #pragma unroll
  for (int q = 0; q < 2; ++q){
    int c = q * 512 + tid;
    int rl = c >> 2;
    int gl = (c & 3) ^ ((rl >> 1) & 3);
    long rsrc;
    if (MODE == 0) rsrc = toklist[e * NTOK + min(m0 + rl, ce - 1)];
    else           rsrc = baseE + min(m0 + rl, ce - 1);
    asrcp[q] = Abuf + (size_t)rsrc * 2048 + gl * 8;
    int n;
    if (MODE == 0) n = fb + (rl >> 6) * 32 + (rl & 31) + ((rl & 32) ? 2048 : 0);
    else           n = fb + rl;
    bsrcp[q] = Wz + (size_t)n * 2048 + gl * 8;
  }
  const int dst16 = tid * 16;

  auto stage = [&](int buf, int piece, int isB, int ksrc){
    unsigned char* base = &smem[buf][piece][0];
    if (isB){
      load_lds16(bsrcp[0] + ksrc, base + dst16);
      load_lds16(bsrcp[1] + ksrc, base + 8192 + dst16);
    } else {
      load_lds16(asrcp[0] + ksrc, base + dst16);
      load_lds16(asrcp[1] + ksrc, base + 8192 + dst16);
    }
  };

  // fragment read offsets (within piece): row*64 + (kq ^ ((row>>1)&3))*16
  const unsigned lbase = lds_addr(&smem[0][0][0]);
  const int kq = l >> 4;
  unsigned aoffs[2][4], boffs[4];
  #pragma unroll
  for (int h = 0; h < 2; ++h)
    #pragma unroll
    for (int m = 0; m < 4; ++m){
      int row = wr * 128 + h * 64 + m * 16 + (l & 15);
      aoffs[h][m] = row * 64 + (unsigned)((kq ^ ((row >> 1) & 3)) * 16);
    }
  #pragma unroll
  for (int n = 0; n < 4; ++n){
    int col = wc * 64 + n * 16 + (l & 15);
    boffs[n] = col * 64 + (unsigned)((kq ^ ((col >> 1) & 3)) * 16);
  }

  f32x4 acc[8][4];
  #pragma unroll
  for (int i = 0; i < 8; ++i)
    #pragma unroll
    for (int j = 0; j < 4; ++j)
      acc[i][j] = (f32x4){0.f, 0.f, 0.f, 0.f};

  // prologue: (0,A0)(0,B0)(0,A1)(0,B1)(1,A0)(1,B0); vmcnt(8) -> kt0 k0 ready
  stage(0, 0, 0, 0);
  stage(0, 2, 1, 0);
  stage(0, 1, 0, 32);
  stage(0, 3, 1, 32);
  stage(1, 0, 0, 64);
  stage(1, 2, 1, 64);
  SCHED();
  asm volatile("s_waitcnt vmcnt(8)");
  SCHED();
  SBAR();
  SCHED();

  #pragma unroll 1
  for (int kt = 0; kt < NKT; ++kt){
    const int buf = kt & 1;
    const unsigned cb = lbase + (unsigned)buf * 65536;
    int kA1 = (kt + 1) * 64 + 32; if (kA1 > 2016) kA1 = 2016;   // dummy tail
    int kN0 = (kt + 2) * 64;      if (kN0 > 2016) kN0 = 2016;
    bf16x8 bfr[4];

    // ---- phase 0: s=0 h=0 ----
    {
      bf16x8 af[4];
      #pragma unroll
      for (int m = 0; m < 4; ++m) af[m] = lds_read16<0>(cb + aoffs[0][m]);
      #pragma unroll
      for (int n = 0; n < 4; ++n) bfr[n] = lds_read16<32768>(cb + boffs[n]);
      stage(buf ^ 1, 1, 0, kA1);          // (kt+1, A_k1)
      SCHED(); SBAR();
      asm volatile("s_waitcnt lgkmcnt(0)");
      SCHED();
      __builtin_amdgcn_s_setprio(1);
      #pragma unroll
      for (int n = 0; n < 4; ++n)
        #pragma unroll
        for (int m = 0; m < 4; ++m)
          acc[m][n] = __builtin_amdgcn_mfma_f32_16x16x32_bf16(af[m], bfr[n], acc[m][n], 0, 0, 0);
      __builtin_amdgcn_s_setprio(0);
      SCHED(); SBAR(); SCHED();
    }
    // ---- phase 1: s=0 h=1 (reuse bfr) ----
    {
      bf16x8 af[4];
      #pragma unroll
      for (int m = 0; m < 4; ++m) af[m] = lds_read16<0>(cb + aoffs[1][m]);
      stage(buf ^ 1, 3, 1, kA1);          // (kt+1, B_k1)
      SCHED(); SBAR();
      asm volatile("s_waitcnt lgkmcnt(0)");
      SCHED();
      __builtin_amdgcn_s_setprio(1);
      #pragma unroll
      for (int n = 0; n < 4; ++n)
        #pragma unroll
        for (int m = 0; m < 4; ++m)
          acc[4 + m][n] = __builtin_amdgcn_mfma_f32_16x16x32_bf16(af[m], bfr[n], acc[4 + m][n], 0, 0, 0);
      __builtin_amdgcn_s_setprio(0);
      SCHED();
      asm volatile("s_waitcnt vmcnt(8)"); // (kt,A1),(kt,B1) ready for phase 2
      SCHED(); SBAR(); SCHED();
    }
    // ---- phase 2: s=1 h=0 ----
    {
      bf16x8 af[4];
      #pragma unroll
      for (int m = 0; m < 4; ++m) af[m] = lds_read16<16384>(cb + aoffs[0][m]);
      #pragma unroll
      for (int n = 0; n < 4; ++n) bfr[n] = lds_read16<49152>(cb + boffs[n]);
      stage(buf, 0, 0, kN0);              // (kt+2, A_k0) over retired slot
      SCHED(); SBAR();
      asm volatile("s_waitcnt lgkmcnt(0)");
      SCHED();
      __builtin_amdgcn_s_setprio(1);
      #pragma unroll
      for (int n = 0; n < 4; ++n)
        #pragma unroll
        for (int m = 0; m < 4; ++m)
          acc[m][n] = __builtin_amdgcn_mfma_f32_16x16x32_bf16(af[m], bfr[n], acc[m][n], 0, 0, 0);
      __builtin_amdgcn_s_setprio(0);
      SCHED(); SBAR(); SCHED();
    }
    // ---- phase 3: s=1 h=1 (reuse bfr) ----
    {
      bf16x8 af[4];
      #pragma unroll
      for (int m = 0; m < 4; ++m) af[m] = lds_read16<16384>(cb + aoffs[1][m]);
      stage(buf, 2, 1, kN0);              // (kt+2, B_k0)
      SCHED(); SBAR();
      asm volatile("s_waitcnt lgkmcnt(0)");
      SCHED();
      __builtin_amdgcn_s_setprio(1);
      #pragma unroll
      for (int n = 0; n < 4; ++n)
        #pragma unroll
        for (int m = 0; m < 4; ++m)
          acc[4 + m][n] = __builtin_amdgcn_mfma_f32_16x16x32_bf16(af[m], bfr[n], acc[4 + m][n], 0, 0, 0);
      __builtin_amdgcn_s_setprio(0);
      SCHED();
      asm volatile("s_waitcnt vmcnt(8)"); // (kt+1,A0),(kt+1,B0) ready for next p0
      SCHED(); SBAR(); SCHED();
    }
  }
  asm volatile("s_waitcnt vmcnt(0)");
  SCHED();
  SBAR();

  const int lq4 = (l >> 4) * 4;
  if (MODE == 0){
    #pragma unroll
    for (int mi = 0; mi < 8; ++mi)
      #pragma unroll
      for (int j = 0; j < 4; ++j){
        int s = m0 + wr * 128 + mi * 16 + lq4 + j;
        if (s < ce){
          size_t rowb = (size_t)(baseE + s) * 2048;
          #pragma unroll
          for (int p = 0; p < 2; ++p){
            float g = acc[mi][p][j];
            float u = acc[mi][p + 2][j];
            float a = 0.5f * g * (1.0f + erff(g * 0.70710678118654752f)) * u; // exact gelu * up
            act[rowb + fb + wc * 32 + p * 16 + (l & 15)] = bf16bits(a);
          }
        }
      }
  } else {
    #pragma unroll
    for (int mi = 0; mi < 8; ++mi)
      #pragma unroll
      for (int j = 0; j < 4; ++j){
        int s = m0 + wr * 128 + mi * 16 + lq4 + j;
        if (s < ce){
          unsigned short* yr = ybuf + (size_t)(baseE + s) * 2048 + fb + wc * 64 + (l & 15);
          #pragma unroll
          for (int ni = 0; ni < 4; ++ni)
            yr[ni * 16] = bf16bits(acc[mi][ni][j]);
        }
      }
  }
}

// ---------------- combine: out[tok] = sum_k slotw[k] * ybuf[slot_k]  (fp32 out, bf16 y)
__global__ __launch_bounds__(256) void combine_kernel(
    const unsigned short* __restrict__ ybuf, const int* __restrict__ tok2slot,
    const float* __restrict__ slotw, const int* __restrict__ basep,
    float* __restrict__ out)
{
  const int n = blockIdx.x * 4 + (threadIdx.x >> 6);
  const int l = threadIdx.x & 63;
  int p0 = tok2slot[2 * n], p1 = tok2slot[2 * n + 1];
  int e0 = p0 >> 16, s0 = p0 & 0xffff;
  int e1 = p1 >> 16, s1 = p1 & 0xffff;
  float w0 = slotw[e0 * NTOK + s0], w1 = slotw[e1 * NTOK + s1];
  const unsigned short* y0 = ybuf + (size_t)(basep[e0] + s0) * 2048;
  const unsigned short* y1 = ybuf + (size_t)(basep[e1] + s1) * 2048;
  float* o = out + (size_t)n * 2048;
  #pragma unroll
  for (int q = 0; q < 4; ++q){
    int c8 = (l + 64 * q) * 8;
    u32x4 a = *(const u32x4*)(y0 + c8);
    u32x4 b = *(const u32x4*)(y1 + c8);
    float rr[8];
    #pragma unroll
    for (int i = 0; i < 4; ++i){
      float a0 = __builtin_bit_cast(float, a[i] << 16);
      float a1 = __builtin_bit_cast(float, a[i] & 0xffff0000u);
      float b0 = __builtin_bit_cast(float, b[i] << 16);
      float b1 = __builtin_bit_cast(float, b[i] & 0xffff0000u);
      rr[2*i]   = w0 * a0 + w1 * b0;
      rr[2*i+1] = w0 * a1 + w1 * b1;
    }
    float4 v0 = {rr[0], rr[1], rr[2], rr[3]};
    float4 v1 = {rr[4], rr[5], rr[6], rr[7]};
    *(float4*)(o + c8) = v0;
    *(float4*)(o + c8 + 4) = v1;
  }
}

extern "C" void kernel_launch(void* const* d_in, const int* in_sizes, int n_in,
                              void* d_out, int out_size, void* d_ws, size_t ws_size,
                              hipStream_t stream)
{
  const float* x   = (const float*)d_in[0];
  const float* rs  = (const float*)d_in[1];
  const float* gw  = (const float*)d_in[2];
  const float* w1  = (const float*)d_in[3];
  const float* w2  = (const float*)d_in[4];
  const float* pes = (const float*)d_in[5];
  float* out = (float*)d_out;

  // ws layout: cnt | base | toklist(128K) | slotw(128K) | tok2slot(32K) |
  //            xbf 16MB | act 32MB | ybuf 32MB | Wt region (EG*16MB)
  char* ws = (char*)d_ws;
  int*   cnt      = (int*)ws;
  int*   basep    = (int*)(ws + 64);
  int*   toklist  = (int*)(ws + 256);
  float* slotw    = (float*)(ws + 256 + (size_t)NE * NTOK * 4);
  int*   tok2slot = (int*)(ws + 256 + 2 * (size_t)NE * NTOK * 4);
  unsigned short* xbf  = (unsigned short*)(ws + 256 + 2 * (size_t)NE * NTOK * 4 + (size_t)NTOK * 8);
  unsigned short* act  = xbf + (size_t)NTOK * DM;
  unsigned short* ybuf = act + (size_t)2 * NTOK * DM;
  unsigned short* wtb  = ybuf + (size_t)2 * NTOK * DM;

  const size_t fixed = (size_t)((char*)wtb - ws);
  const size_t per_e = (size_t)4096 * 2048 * 2;   // 16 MiB (W1 per expert; W2 uses half)
  int EG = NE;
  while (EG > 1 && fixed + (size_t)EG * per_e > ws_size) EG >>= 1;

  hipMemsetAsync(cnt, 0, 64, stream);
  router_kernel<<<NTOK / 4, 256, 0, stream>>>(x, rs, gw, pes, xbf, cnt, toklist, slotw, tok2slot);
  scan_kernel<<<1, 64, 0, stream>>>(cnt, basep);

  for (int g = 0; g < NE; g += EG){
    conv_transpose_kernel<<<dim3(64, 32, EG), 256, 0, stream>>>(
        w1 + (size_t)g * 2048 * 4096, wtb, 4096);
    moe_gemm<0><<<dim3(16, 16, EG), 512, 0, stream>>>(
        xbf, wtb, act, ybuf, cnt, basep, toklist, g);
  }
  for (int g = 0; g < NE; g += EG){
    conv_transpose_kernel<<<dim3(32, 32, EG), 256, 0, stream>>>(
        w2 + (size_t)g * 2048 * 2048, wtb, 2048);
    moe_gemm<1><<<dim3(8, 16, EG), 512, 0, stream>>>(
        act, wtb, act, ybuf, cnt, basep, toklist, g);
  }
  combine_kernel<<<NTOK / 4, 256, 0, stream>>>(ybuf, tok2slot, slotw, basep, out);
}